// Round 10
// baseline (372.556 us; speedup 1.0000x reference)
//
#include <hip/hip_runtime.h>
#include <hip/hip_bf16.h>
#include <math.h>

namespace {

constexpr int B_ = 2, P_ = 12, N_ = 170, DM_ = 64, H_ = 8, DK_ = 8, DH_ = 32, DF_ = 256;
constexpr int T_ = B_ * P_ * N_;        // 4080 tokens
constexpr float SQRT_DK = 2.8284271247461903f;

constexpr int NG_ = 12;                 // 192 output cols / 16
constexpr int NC_ = 66;                 // 2112 K / 32
constexpr int WFRAG_G = NG_ * NC_ * 64 * 8;   // shorts per graph = 405504

typedef __attribute__((ext_vector_type(4))) short short4v;
typedef __attribute__((ext_vector_type(8))) short short8v;
typedef __attribute__((ext_vector_type(4))) float float4v;

// float -> bf16 bits, round-to-nearest-even
__device__ __forceinline__ unsigned short f2bf(float x) {
    union { float f; unsigned int u; } c; c.f = x;
    unsigned int r = (c.u + 0x7FFFu + ((c.u >> 16) & 1u)) >> 16;
    return (unsigned short)r;
}

// ---------- merged one-time prep: w2/b2 permute (y==0) + 3x meta hidden (y>=1) ----------
__global__ void k_pre(const float* __restrict__ c_x,
                      const float* __restrict__ w1a, const float* __restrict__ b1a,
                      const float* __restrict__ w1b, const float* __restrict__ b1b,
                      const float* __restrict__ w1c, const float* __restrict__ b1c,
                      const float* __restrict__ w2a, const float* __restrict__ b2a,
                      const float* __restrict__ w2b, const float* __restrict__ b2b,
                      const float* __restrict__ w2c, const float* __restrict__ b2c,
                      float* __restrict__ hra, float* __restrict__ hrb,
                      float* __restrict__ hrc, unsigned short* __restrict__ Wfrag) {
    if (blockIdx.y == 0) {
        int idx = blockIdx.x * 256 + threadIdx.x;   // ((g*12+ng)*66+c)*64 + lane
        if (idx >= 3 * NG_ * NC_ * 64) return;
        int lane = idx & 63;
        int c = (idx >> 6) % NC_;
        int ng = (idx >> 6) / NC_ % NG_;
        int g = idx / (64 * NC_ * NG_);
        const float* w2 = g == 0 ? w2a : (g == 1 ? w2b : w2c);
        const float* b2 = g == 0 ? b2a : (g == 1 ? b2b : b2c);
        int m = ng * 16 + (lane & 15);
        int u = c >> 1;                              // jh
        int d0 = (c & 1) * 32 + (lane >> 4) * 8;
        const float* src = (u < DH_) ? (w2 + u * 12288 + m * 64 + d0) : (b2 + m * 64 + d0);
        short8v o;
        #pragma unroll
        for (int j = 0; j < 8; ++j) o[j] = (short)f2bf(src[j]);
        *(short8v*)(Wfrag + (size_t)idx * 8) = o;
    } else {
        int z = blockIdx.y - 1;
        const float* w1 = z == 0 ? w1a : (z == 1 ? w1b : w1c);
        const float* b1 = z == 0 ? b1a : (z == 1 ? b1b : b1c);
        float* hr = z == 0 ? hra : (z == 1 ? hrb : hrc);
        int idx = blockIdx.x * 256 + threadIdx.x;          // t*32 + j
        if (idx >= T_ * DH_) return;
        int t = idx / DH_, j = idx % DH_;
        float acc = b1[j];
        const float* cx = c_x + t * DM_;
        #pragma unroll
        for (int d = 0; d < DM_; ++d) acc += cx[d] * w1[d * DH_ + j];
        hr[idx] = fmaxf(acc, 0.f);
    }
}

// ---------- meta+mhlin GEMM v5: 32-col tiles (2x waves), 2-deep register prefetch ----------
__global__ __launch_bounds__(256) void k_meta_gemm2(
    const float* __restrict__ hr0, const float* __restrict__ hr1,
    const float* __restrict__ xin,
    const unsigned short* __restrict__ Wf0, const unsigned short* __restrict__ Wf1,
    float* __restrict__ out0, float* __restrict__ out1) {
    const int bz = blockIdx.z;
    const float* hr = bz ? hr1 : hr0;
    const unsigned short* Wf = bz ? Wf1 : Wf0;
    float* out = bz ? out1 : out0;

    const int tid = threadIdx.x;
    const int wv = tid >> 6, lane = tid & 63;
    const int l15 = lane & 15, quad = lane >> 4;
    const int g16 = blockIdx.x * 4 + wv;
    if (g16 >= 255) return;                      // 255 groups of 16 tokens; no barriers
    const int t = g16 * 16 + l15;
    const int nb = blockIdx.y;                   // 0..5 (32 cols each)

    const float* xp = xin + t * 64 + quad * 8;
    float4v xa = *(const float4v*)(xp);
    float4v xb = *(const float4v*)(xp + 4);
    float4v xc = *(const float4v*)(xp + 32);
    float4v xd = *(const float4v*)(xp + 36);
    float xr[16] = {xa.x, xa.y, xa.z, xa.w, xb.x, xb.y, xb.z, xb.w,
                    xc.x, xc.y, xc.z, xc.w, xd.x, xd.y, xd.z, xd.w};

    const float* hrp = hr + t * 32;
    float hrbuf[32];
    #pragma unroll
    for (int i = 0; i < 8; ++i) {
        float4v h4 = *(const float4v*)(hrp + i * 4);
        hrbuf[i * 4 + 0] = h4.x; hrbuf[i * 4 + 1] = h4.y;
        hrbuf[i * 4 + 2] = h4.z; hrbuf[i * 4 + 3] = h4.w;
    }

    float4v acc[2] = {{0.f,0.f,0.f,0.f},{0.f,0.f,0.f,0.f}};

    const unsigned short* wb = Wf + ((size_t)(nb * 2) * NC_ * 64 + lane) * 8;
    const size_t qstride = (size_t)NC_ * 64 * 8;   // ng -> ng+1
    const size_t cstride = 64 * 8;                 // c -> c+1

    short8v b[2][4];
    {
        const unsigned short* wc = wb;
        #pragma unroll
        for (int q = 0; q < 2; ++q) {
            b[0][2 * q]     = *(const short8v*)(wc + q * qstride);
            b[0][2 * q + 1] = *(const short8v*)(wc + q * qstride + cstride);
        }
    }
    #pragma unroll
    for (int u = 0; u < 33; ++u) {
        const int cur = u & 1, nxt = cur ^ 1;
        if (u + 1 < 33) {       // issue next-step loads FIRST (hidden under compute)
            const unsigned short* wc = wb + (size_t)(2 * (u + 1)) * cstride;
            #pragma unroll
            for (int q = 0; q < 2; ++q) {
                b[nxt][2 * q]     = *(const short8v*)(wc + q * qstride);
                b[nxt][2 * q + 1] = *(const short8v*)(wc + q * qstride + cstride);
            }
        }
        float hrv = (u < 32) ? hrbuf[u] : 1.0f;    // u=32: bias row
        short8v a0, a1;
        #pragma unroll
        for (int j = 0; j < 8; ++j) {
            a0[j] = (short)f2bf(hrv * xr[j]);
            a1[j] = (short)f2bf(hrv * xr[8 + j]);
        }
        #pragma unroll
        for (int q = 0; q < 2; ++q) {
            acc[q] = __builtin_amdgcn_mfma_f32_16x16x32_bf16(a0, b[cur][2 * q],     acc[q], 0, 0, 0);
            acc[q] = __builtin_amdgcn_mfma_f32_16x16x32_bf16(a1, b[cur][2 * q + 1], acc[q], 0, 0, 0);
        }
    }

    // D: col=lane&15 (n), row=quad*4+r (token)  [learn_hip m89/m91]
    #pragma unroll
    for (int q = 0; q < 2; ++q) {
        #pragma unroll
        for (int r = 0; r < 4; ++r) {
            int tt = g16 * 16 + quad * 4 + r;
            out[tt * 192 + nb * 32 + q * 16 + l15] = acc[q][r];
        }
    }
}

// ---------- retnet retention v3: 768 thr, wave = one q, S staged once ----------
__global__ __launch_bounds__(768) void k_retnet(const float* __restrict__ qkv,
                                                const float* __restrict__ Dm,
                                                float* __restrict__ att) {
    const int bn = blockIdx.x;           // b*N + n
    const int b = bn / N_, n = bn % N_;
    __shared__ float S[12][192];
    __shared__ float Ds[8 * 145];
    const int tid = threadIdx.x;
    for (int e = tid; e < 12 * 192; e += 768) {
        int p = e / 192, c = e % 192;
        S[p][c] = qkv[((size_t)((b * P_ + p) * N_ + n)) * 192 + c];
    }
    for (int e = tid; e < 1152; e += 768) {
        Ds[(e / 144) * 145 + (e % 144)] = Dm[e];
    }
    __syncthreads();
    const int q = tid >> 6;              // wave index == q (0..11)
    const int lane = tid & 63;
    const int h = lane >> 3, k = lane & 7;
    float Qv = S[q][h * 8 + k];
    float r[P_];
    float rsum = 0.f;
    #pragma unroll
    for (int p = 0; p < P_; ++p) {
        float prod = Qv * S[p][64 + h * 8 + k];
        prod += __shfl_xor(prod, 1, 64);
        prod += __shfl_xor(prod, 2, 64);
        prod += __shfl_xor(prod, 4, 64);
        float s = (prod / SQRT_DK) * Ds[h * 145 + q * 12 + p];
        r[p] = s; rsum += s;
    }
    float rs = fmaxf(fabsf(rsum), 1.0f);
    float acc = 0.f;
    #pragma unroll
    for (int p = 0; p < P_; ++p) acc += (r[p] / rs) * S[p][128 + h * 8 + k];
    att[((size_t)((b * P_ + q) * N_ + n)) * 64 + lane] = acc;
}

// ---------- temporal enc-dec attention v3: 768 thr, wave = one q ----------
__global__ __launch_bounds__(768) void k_temporal(const float* __restrict__ qkv,
                                                  float* __restrict__ att) {
    const int bn = blockIdx.x;
    const int b = bn / N_, n = bn % N_;
    __shared__ float S[12][192];
    const int tid = threadIdx.x;
    for (int e = tid; e < 12 * 192; e += 768) {
        int p = e / 192, c = e % 192;
        S[p][c] = qkv[((size_t)((b * P_ + p) * N_ + n)) * 192 + c];
    }
    __syncthreads();
    const int q = tid >> 6;
    const int lane = tid & 63;
    const int h = lane >> 3, k = lane & 7;
    float Qv = S[q][h * 8 + k];
    float s[P_];
    float mx = -1e30f;
    #pragma unroll
    for (int p = 0; p < P_; ++p) {
        float prod = Qv * S[p][64 + h * 8 + k];
        prod += __shfl_xor(prod, 1, 64);
        prod += __shfl_xor(prod, 2, 64);
        prod += __shfl_xor(prod, 4, 64);
        float v = prod / SQRT_DK;
        s[p] = v; mx = fmaxf(mx, v);
    }
    float den = 0.f, acc = 0.f;
    #pragma unroll
    for (int p = 0; p < P_; ++p) {
        float e = expf(s[p] - mx);
        den += e;
        acc += e * S[p][128 + h * 8 + k];
    }
    att[((size_t)((b * P_ + q) * N_ + n)) * 64 + lane] = acc / den;
}

// ---------- spatial attention: SPARSE. one wave per (g, bp, row i) ----------
__global__ __launch_bounds__(256) void k_spatial_sparse(
    const float* __restrict__ qkvA, const float* __restrict__ qkvB,
    const float* __restrict__ Tm, const float* __restrict__ Am,
    float* __restrict__ attA, float* __restrict__ attB) {
    const int bp = blockIdx.y;          // 0..23
    const int g = blockIdx.z;           // 0: predefined T, 1: adaptive A
    const float* qkv = g ? qkvB : qkvA;
    float* att = g ? attB : attA;

    __shared__ int2 elist[4][176];      // per-wave (j, weight-bits)

    const int tid = threadIdx.x;
    const int wv = tid >> 6, lane = tid & 63;
    const int i = blockIdx.x * 4 + wv;
    if (i >= N_) return;                // no __syncthreads anywhere: safe

    int2* el = elist[wv];
    const float* Trow = g ? (Am + (size_t)(bp * N_ + i) * N_) : (Tm + (size_t)i * N_);
    int nnz = 0;
    #pragma unroll
    for (int c = 0; c < 3; ++c) {
        int j = c * 64 + lane;
        float w = (j < N_) ? Trow[j] : 0.f;
        unsigned long long m = __ballot(w != 0.f);
        if (w != 0.f) {
            int pos = nnz + (int)__popcll(m & ((1ull << lane) - 1ull));
            el[pos] = make_int2(j, __float_as_int(w));
        }
        nnz += (int)__popcll(m);
    }

    const float q = qkv[(size_t)(bp * N_ + i) * 192 + lane];  // Q[i, h*8+k]
    float m = 0.f;                       // masked zeros enter the row max
    float den = 0.f, acc = 0.f;
    int e = 0;
    for (; e + 1 < nnz; e += 2) {
        int2 e0 = el[e], e1 = el[e + 1];
        const float* r0 = qkv + (size_t)(bp * N_ + e0.x) * 192;
        const float* r1 = qkv + (size_t)(bp * N_ + e1.x) * 192;
        float k0 = r0[64 + lane], v0 = r0[128 + lane];
        float k1 = r1[64 + lane], v1 = r1[128 + lane];
        float p0 = q * k0, p1 = q * k1;
        p0 += __shfl_xor(p0, 1, 64); p1 += __shfl_xor(p1, 1, 64);
        p0 += __shfl_xor(p0, 2, 64); p1 += __shfl_xor(p1, 2, 64);
        p0 += __shfl_xor(p0, 4, 64); p1 += __shfl_xor(p1, 4, 64);
        float s0 = p0 / SQRT_DK, s1 = p1 / SQRT_DK;
        float mn = fmaxf(m, fmaxf(s0, s1));          // -> v_max3
        float cs = expf(m - mn);
        float x0 = (s0 != 0.f) ? expf(s0 - mn) : 0.f;
        float x1 = (s1 != 0.f) ? expf(s1 - mn) : 0.f;
        den = den * cs + x0 + x1;
        acc = acc * cs + x0 * __int_as_float(e0.y) * v0
                       + x1 * __int_as_float(e1.y) * v1;
        m = mn;
    }
    if (e < nnz) {
        int2 e0 = el[e];
        const float* r0 = qkv + (size_t)(bp * N_ + e0.x) * 192;
        float k0 = r0[64 + lane], v0 = r0[128 + lane];
        float p0 = q * k0;
        p0 += __shfl_xor(p0, 1, 64);
        p0 += __shfl_xor(p0, 2, 64);
        p0 += __shfl_xor(p0, 4, 64);
        float s0 = p0 / SQRT_DK;
        float mn = fmaxf(m, s0);
        float cs = expf(m - mn);
        float x0 = (s0 != 0.f) ? expf(s0 - mn) : 0.f;
        den = den * cs + x0;
        acc = acc * cs + x0 * __int_as_float(e0.y) * v0;
    }

    att[(size_t)(bp * N_ + i) * 64 + lane] = acc / (den + 1e-5f);
}

// ---------- gdc8 for FOUR tokens sharing each weight load ----------
__device__ __forceinline__ void gdc8x4(const float* dv0, const float* dv1,
                                       const float* dv2, const float* dv3,
                                       const float* W1, const float* W2, int dm,
                                       float& r0, float& r1, float& r2, float& r3) {
    float a0[8], s0[8], a1[8], s1[8], a2[8], s2[8], a3[8], s3[8];
    #pragma unroll
    for (int g = 0; g < 8; ++g) {
        float aa0 = 0.f, ss0 = 0.f, aa1 = 0.f, ss1 = 0.f;
        float aa2 = 0.f, ss2 = 0.f, aa3 = 0.f, ss3 = 0.f;
        #pragma unroll
        for (int c = 0; c < 8; ++c) {
            float w1v = W1[(g * 8 + c) * 64 + dm];
            float w2v = W2[(g * 8 + c) * 64 + dm];
            float d0 = dv0[g * 8 + c], d1 = dv1[g * 8 + c];
            float d2 = dv2[g * 8 + c], d3 = dv3[g * 8 + c];
            aa0 += d0 * w1v; ss0 += d0 * w2v;
            aa1 += d1 * w1v; ss1 += d1 * w2v;
            aa2 += d2 * w1v; ss2 += d2 * w2v;
            aa3 += d3 * w1v; ss3 += d3 * w2v;
        }
        a0[g] = aa0; s0[g] = fmaxf(ss0, 0.f);
        a1[g] = aa1; s1[g] = fmaxf(ss1, 0.f);
        a2[g] = aa2; s2[g] = fmaxf(ss2, 0.f);
        a3[g] = aa3; s3[g] = fmaxf(ss3, 0.f);
    }
    float mx0 = s0[0], mx1 = s1[0], mx2 = s2[0], mx3 = s3[0];
    #pragma unroll
    for (int g = 1; g < 8; ++g) {
        mx0 = fmaxf(mx0, s0[g]); mx1 = fmaxf(mx1, s1[g]);
        mx2 = fmaxf(mx2, s2[g]); mx3 = fmaxf(mx3, s3[g]);
    }
    float den0 = 0.f, o0 = 0.f, den1 = 0.f, o1 = 0.f;
    float den2 = 0.f, o2 = 0.f, den3 = 0.f, o3 = 0.f;
    #pragma unroll
    for (int g = 0; g < 8; ++g) {
        float e0 = expf(s0[g] - mx0); den0 += e0; o0 += a0[g] * e0;
        float e1 = expf(s1[g] - mx1); den1 += e1; o1 += a1[g] * e1;
        float e2 = expf(s2[g] - mx2); den2 += e2; o2 += a2[g] * e2;
        float e3 = expf(s3[g] - mx3); den3 += e3; o3 += a3[g] * e3;
    }
    r0 = o0 / den0; r1 = o1 / den1; r2 = o2 / den2; r3 = o3 / den3;
}

__device__ __forceinline__ float ln_out(float r, int dm, const float* g, const float* b) {
    float m = r, m2 = r * r;
    #pragma unroll
    for (int off = 32; off; off >>= 1) { m += __shfl_xor(m, off, 64); m2 += __shfl_xor(m2, off, 64); }
    m *= (1.f / 64.f); m2 *= (1.f / 64.f);
    float var = m2 - m * m;
    return (r - m) * rsqrtf(var + 1e-5f) * g[dm] + b[dm];
}

// ---------- gdc + swish + residual + LN, 4 tokens/wave ----------
__global__ __launch_bounds__(64) void k_gsl(const float* __restrict__ att,
    const float* __restrict__ xin,
    const float* W1, const float* W2,
    const float* wg, const float* bg,
    const float* wo, const float* bo,
    const float* lng, const float* lnb, float* __restrict__ xout) {
    const int t0 = blockIdx.x * 4, dm = threadIdx.x;
    __shared__ float dv[4][64], xv[4][64], sw[4][64];
    #pragma unroll
    for (int s = 0; s < 4; ++s) {
        dv[s][dm] = att[(t0 + s) * 64 + dm];
        xv[s][dm] = xin[(t0 + s) * 64 + dm];
    }
    __syncthreads();
    float o0, o1, o2, o3;
    gdc8x4(dv[0], dv[1], dv[2], dv[3], W1, W2, dm, o0, o1, o2, o3);
    float hg0 = bg[dm], hg1 = hg0, hg2 = hg0, hg3 = hg0;
    #pragma unroll
    for (int d = 0; d < 64; ++d) {
        float w = wg[d * 64 + dm];
        hg0 += xv[0][d] * w; hg1 += xv[1][d] * w;
        hg2 += xv[2][d] * w; hg3 += xv[3][d] * w;
    }
    hg0 *= o0; hg1 *= o1; hg2 *= o2; hg3 *= o3;
    sw[0][dm] = hg0 / (1.f + expf(-hg0));
    sw[1][dm] = hg1 / (1.f + expf(-hg1));
    sw[2][dm] = hg2 / (1.f + expf(-hg2));
    sw[3][dm] = hg3 / (1.f + expf(-hg3));
    __syncthreads();
    float ov0 = bo[dm], ov1 = ov0, ov2 = ov0, ov3 = ov0;
    #pragma unroll
    for (int d = 0; d < 64; ++d) {
        float w = wo[d * 64 + dm];
        ov0 += sw[0][d] * w; ov1 += sw[1][d] * w;
        ov2 += sw[2][d] * w; ov3 += sw[3][d] * w;
    }
    xout[(t0 + 0) * 64 + dm] = ln_out(ov0 + xv[0][dm], dm, lng, lnb);
    xout[(t0 + 1) * 64 + dm] = ln_out(ov1 + xv[1][dm], dm, lng, lnb);
    xout[(t0 + 2) * 64 + dm] = ln_out(ov2 + xv[2][dm], dm, lng, lnb);
    xout[(t0 + 3) * 64 + dm] = ln_out(ov3 + xv[3][dm], dm, lng, lnb);
}

// ---------- spatial tail + qkv proj, 4 tokens/wave ----------
__global__ __launch_bounds__(64) void k_spatial_fuse_qkv(
    const float* __restrict__ att0, const float* __restrict__ att1,
    const float* __restrict__ x1,
    const float* gs0_W1, const float* gs0_W2,
    const float* gs1_W1, const float* gs1_W2,
    const float* g2_W1, const float* g2_W2,
    const float* wg, const float* bg,
    const float* wo, const float* bo,
    const float* lng, const float* lnb,
    const float* __restrict__ enc,
    const float* wqm, const float* wkm, const float* wvm,
    float* __restrict__ x2f, float* __restrict__ qkv) {
    const int t0 = blockIdx.x * 4, dm = threadIdx.x;
    __shared__ float d0s[4][64], d1s[4][64], xv[4][64], ev[4][64];
    __shared__ float o0s[4][64], o1s[4][64], sw[4][64], x2s[4][64];
    #pragma unroll
    for (int s = 0; s < 4; ++s) {
        d0s[s][dm] = att0[(t0 + s) * 64 + dm];
        d1s[s][dm] = att1[(t0 + s) * 64 + dm];
        xv[s][dm]  = x1[(t0 + s) * 64 + dm];
        ev[s][dm]  = enc[(t0 + s) * 64 + dm];
    }
    __syncthreads();
    float g0[4], g1[4];
    gdc8x4(d0s[0], d0s[1], d0s[2], d0s[3], gs0_W1, gs0_W2, dm, g0[0], g0[1], g0[2], g0[3]);
    gdc8x4(d1s[0], d1s[1], d1s[2], d1s[3], gs1_W1, gs1_W2, dm, g1[0], g1[1], g1[2], g1[3]);
    #pragma unroll
    for (int s = 0; s < 4; ++s) { o0s[s][dm] = g0[s]; o1s[s][dm] = g1[s]; }
    __syncthreads();
    // g2 (G=2, C=64) for 4 tokens; 4 weight loads per c shared
    float aA[4] = {0.f, 0.f, 0.f, 0.f}, sA[4] = {0.f, 0.f, 0.f, 0.f};
    float aB[4] = {0.f, 0.f, 0.f, 0.f}, sB[4] = {0.f, 0.f, 0.f, 0.f};
    #pragma unroll
    for (int c = 0; c < 64; ++c) {
        float wA0 = g2_W1[c * 64 + dm],        wS0 = g2_W2[c * 64 + dm];
        float wA1 = g2_W1[(64 + c) * 64 + dm], wS1 = g2_W2[(64 + c) * 64 + dm];
        #pragma unroll
        for (int s = 0; s < 4; ++s) {
            float v0 = o0s[s][c], v1 = o1s[s][c];
            aA[s] += v0 * wA0; sA[s] += v0 * wS0;
            aB[s] += v1 * wA1; sB[s] += v1 * wS1;
        }
    }
    float og[4];
    #pragma unroll
    for (int s = 0; s < 4; ++s) {
        float p = fmaxf(sA[s], 0.f), qv = fmaxf(sB[s], 0.f);
        float mx = fmaxf(p, qv);
        float e0 = expf(p - mx), e1 = expf(qv - mx);
        og[s] = (aA[s] * e0 + aB[s] * e1) / (e0 + e1);
    }
    float hg[4] = {bg[dm], bg[dm], bg[dm], bg[dm]};
    #pragma unroll
    for (int d = 0; d < 64; ++d) {
        float w = wg[d * 64 + dm];
        #pragma unroll
        for (int s = 0; s < 4; ++s) hg[s] += xv[s][d] * w;
    }
    #pragma unroll
    for (int s = 0; s < 4; ++s) {
        float h = hg[s] * og[s];
        sw[s][dm] = h / (1.f + expf(-h));
    }
    __syncthreads();
    float ov[4] = {bo[dm], bo[dm], bo[dm], bo[dm]};
    #pragma unroll
    for (int d = 0; d < 64; ++d) {
        float w = wo[d * 64 + dm];
        #pragma unroll
        for (int s = 0; s < 4; ++s) ov[s] += sw[s][d] * w;
    }
    float x2r[4];
    #pragma unroll
    for (int s = 0; s < 4; ++s) {
        x2r[s] = ln_out(ov[s] + xv[s][dm], dm, lng, lnb);
        x2f[(t0 + s) * 64 + dm] = x2r[s];
        x2s[s][dm] = x2r[s];
    }
    __syncthreads();
    // q/k/v projections (q from x2, k/v from enc), weight loads shared
    float aq[4] = {0.f, 0.f, 0.f, 0.f}, ak[4] = {0.f, 0.f, 0.f, 0.f}, av[4] = {0.f, 0.f, 0.f, 0.f};
    #pragma unroll
    for (int d = 0; d < 64; ++d) {
        float wq_ = wqm[d * 64 + dm];
        float wk_ = wkm[d * 64 + dm];
        float wv_ = wvm[d * 64 + dm];
        #pragma unroll
        for (int s = 0; s < 4; ++s) {
            aq[s] += x2s[s][d] * wq_;
            ak[s] += ev[s][d] * wk_;
            av[s] += ev[s][d] * wv_;
        }
    }
    #pragma unroll
    for (int s = 0; s < 4; ++s) {
        qkv[(t0 + s) * 192 + dm] = aq[s];
        qkv[(t0 + s) * 192 + 64 + dm] = ak[s];
        qkv[(t0 + s) * 192 + 128 + dm] = av[s];
    }
}

// ---------- stage-3 tail + FFN, 4 tokens/wave (x3 never hits global) ----------
__global__ __launch_bounds__(64) void k_gsl_ffn(const float* __restrict__ att,
    const float* __restrict__ xin,
    const float* W1, const float* W2,
    const float* wg, const float* bg,
    const float* wo, const float* bo,
    const float* lng, const float* lnb,
    const float* w1, const float* b1,
    const float* w2, const float* b2,
    const float* lnfg, const float* lnfb,
    float* __restrict__ out) {
    const int t0 = blockIdx.x * 4, dm = threadIdx.x;
    __shared__ float dv[4][64], xv[4][64], sw[4][64];
    __shared__ float x3s[4][64], hv[4][256];
    #pragma unroll
    for (int s = 0; s < 4; ++s) {
        dv[s][dm] = att[(t0 + s) * 64 + dm];
        xv[s][dm] = xin[(t0 + s) * 64 + dm];
    }
    __syncthreads();
    float o0, o1, o2, o3;
    gdc8x4(dv[0], dv[1], dv[2], dv[3], W1, W2, dm, o0, o1, o2, o3);
    float hg0 = bg[dm], hg1 = hg0, hg2 = hg0, hg3 = hg0;
    #pragma unroll
    for (int d = 0; d < 64; ++d) {
        float w = wg[d * 64 + dm];
        hg0 += xv[0][d] * w; hg1 += xv[1][d] * w;
        hg2 += xv[2][d] * w; hg3 += xv[3][d] * w;
    }
    hg0 *= o0; hg1 *= o1; hg2 *= o2; hg3 *= o3;
    sw[0][dm] = hg0 / (1.f + expf(-hg0));
    sw[1][dm] = hg1 / (1.f + expf(-hg1));
    sw[2][dm] = hg2 / (1.f + expf(-hg2));
    sw[3][dm] = hg3 / (1.f + expf(-hg3));
    __syncthreads();
    float ov0 = bo[dm], ov1 = ov0, ov2 = ov0, ov3 = ov0;
    #pragma unroll
    for (int d = 0; d < 64; ++d) {
        float w = wo[d * 64 + dm];
        ov0 += sw[0][d] * w; ov1 += sw[1][d] * w;
        ov2 += sw[2][d] * w; ov3 += sw[3][d] * w;
    }
    float x3r[4];
    x3r[0] = ln_out(ov0 + xv[0][dm], dm, lng, lnb);
    x3r[1] = ln_out(ov1 + xv[1][dm], dm, lng, lnb);
    x3r[2] = ln_out(ov2 + xv[2][dm], dm, lng, lnb);
    x3r[3] = ln_out(ov3 + xv[3][dm], dm, lng, lnb);
    #pragma unroll
    for (int s = 0; s < 4; ++s) x3s[s][dm] = x3r[s];
    __syncthreads();
    // ---- FFN, w1/w2 loads shared across 4 tokens ----
    #pragma unroll
    for (int e = 0; e < 4; ++e) {
        int j = e * 64 + dm;
        float a0 = b1[j], a1 = a0, a2 = a0, a3 = a0;
        #pragma unroll
        for (int d = 0; d < 64; ++d) {
            float w = w1[d * 256 + j];
            a0 += x3s[0][d] * w; a1 += x3s[1][d] * w;
            a2 += x3s[2][d] * w; a3 += x3s[3][d] * w;
        }
        hv[0][j] = fmaxf(a0, 0.f);
        hv[1][j] = fmaxf(a1, 0.f);
        hv[2][j] = fmaxf(a2, 0.f);
        hv[3][j] = fmaxf(a3, 0.f);
    }
    __syncthreads();
    float a0 = b2[dm], a1 = a0, a2 = a0, a3 = a0;
    for (int j = 0; j < 256; ++j) {
        float w = w2[j * 64 + dm];
        a0 += hv[0][j] * w; a1 += hv[1][j] * w;
        a2 += hv[2][j] * w; a3 += hv[3][j] * w;
    }
    out[(t0 + 0) * 64 + dm] = ln_out(a0 + x3r[0], dm, lnfg, lnfb);
    out[(t0 + 1) * 64 + dm] = ln_out(a1 + x3r[1], dm, lnfg, lnfb);
    out[(t0 + 2) * 64 + dm] = ln_out(a2 + x3r[2], dm, lnfg, lnfb);
    out[(t0 + 3) * 64 + dm] = ln_out(a3 + x3r[3], dm, lnfg, lnfb);
}

} // namespace

extern "C" void kernel_launch(void* const* d_in, const int* in_sizes, int n_in,
                              void* d_out, int out_size, void* d_ws, size_t ws_size,
                              hipStream_t stream) {
    (void)in_sizes; (void)n_in; (void)out_size; (void)ws_size;
    const float* x    = (const float*)d_in[0];
    const float* c_x  = (const float*)d_in[1];
    const float* enc  = (const float*)d_in[2];
    const float* Tm   = (const float*)d_in[3];
    const float* Am   = (const float*)d_in[4];
    const float* Dm   = (const float*)d_in[5];
    const float* mr_w1 = (const float*)d_in[6];
    const float* mr_b1 = (const float*)d_in[7];
    const float* mr_w2 = (const float*)d_in[8];
    const float* mr_b2 = (const float*)d_in[9];
    const float* ms0_w1 = (const float*)d_in[10];
    const float* ms0_b1 = (const float*)d_in[11];
    const float* ms0_w2 = (const float*)d_in[12];
    const float* ms0_b2 = (const float*)d_in[13];
    const float* ms1_w1 = (const float*)d_in[14];
    const float* ms1_b1 = (const float*)d_in[15];
    const float* ms1_w2 = (const float*)d_in[16];
    const float* ms1_b2 = (const float*)d_in[17];
    const float* gr_W1 = (const float*)d_in[18];
    const float* gr_W2 = (const float*)d_in[19];
    const float* gs0_W1 = (const float*)d_in[20];
    const float* gs0_W2 = (const float*)d_in[21];
    const float* gs1_W1 = (const float*)d_in[22];
    const float* gs1_W2 = (const float*)d_in[23];
    const float* g2_W1 = (const float*)d_in[24];
    const float* g2_W2 = (const float*)d_in[25];
    const float* ge_W1 = (const float*)d_in[26];
    const float* ge_W2 = (const float*)d_in[27];
    const float* swr_wg = (const float*)d_in[28];
    const float* swr_bg = (const float*)d_in[29];
    const float* swr_wo = (const float*)d_in[30];
    const float* swr_bo = (const float*)d_in[31];
    const float* sws_wg = (const float*)d_in[32];
    const float* sws_bg = (const float*)d_in[33];
    const float* sws_wo = (const float*)d_in[34];
    const float* sws_bo = (const float*)d_in[35];
    const float* swe_wg = (const float*)d_in[36];
    const float* swe_bg = (const float*)d_in[37];
    const float* swe_wo = (const float*)d_in[38];
    const float* swe_bo = (const float*)d_in[39];
    const float* lnr_g = (const float*)d_in[40];
    const float* lnr_b = (const float*)d_in[41];
    const float* lns_g = (const float*)d_in[42];
    const float* lns_b = (const float*)d_in[43];
    const float* lne_g = (const float*)d_in[44];
    const float* lne_b = (const float*)d_in[45];
    const float* lnf_g = (const float*)d_in[46];
    const float* lnf_b = (const float*)d_in[47];
    const float* wq = (const float*)d_in[48];
    const float* wk = (const float*)d_in[49];
    const float* wv = (const float*)d_in[50];
    const float* f_w1 = (const float*)d_in[51];
    const float* f_b1 = (const float*)d_in[52];
    const float* f_w2 = (const float*)d_in[53];
    const float* f_b2 = (const float*)d_in[54];

    // workspace layout (~16.2 MB)
    float* ws   = (float*)d_ws;
    float* hr   = ws;                 // stage-2 graph0 hr
    float* hr2  = hr   + T_ * DH_;    // stage-2 graph1 hr
    float* qkva = hr2  + T_ * DH_;
    float* qkvb = qkva + T_ * 192;
    float* atta = qkvb + T_ * 192;
    float* attb = atta + T_ * DM_;    // also reused as stage-1 hr buffer
    float* x1f  = attb + T_ * DM_;
    float* x2f  = x1f  + T_ * DM_;
    float* x3f  = x2f  + T_ * DM_;    // unused now (kept for layout stability)
    unsigned short* Wfrag = (unsigned short*)(x3f + T_ * DM_);  // 3 graphs, 2.4 MB
    float* hr_r = attb;               // consumed before k_spatial_sparse writes attb

    // one launch: w2/b2 permute (y=0) + all three meta-hiddens (y=1..3)
    k_pre<<<dim3(594, 4), 256, 0, stream>>>(
        c_x, mr_w1, mr_b1, ms0_w1, ms0_b1, ms1_w1, ms1_b1,
        mr_w2, mr_b2, ms0_w2, ms0_b2, ms1_w2, ms1_b2,
        hr_r, hr, hr2, Wfrag);

    // ---- stage 1: retnet retention ----
    k_meta_gemm2<<<dim3(64, 6, 1), 256, 0, stream>>>(
        hr_r, hr_r, x, Wfrag, Wfrag, qkva, qkva);
    k_retnet<<<B_ * N_, 768, 0, stream>>>(qkva, Dm, atta);
    k_gsl<<<T_ / 4, 64, 0, stream>>>(atta, x, gr_W1, gr_W2, swr_wg, swr_bg,
                                     swr_wo, swr_bo, lnr_g, lnr_b, x1f);

    // ---- stage 2: spatial (sparse edge walk) + fused tail + qkv projection ----
    k_meta_gemm2<<<dim3(64, 6, 2), 256, 0, stream>>>(
        hr, hr2, x1f, Wfrag + WFRAG_G, Wfrag + 2 * WFRAG_G, qkva, qkvb);
    k_spatial_sparse<<<dim3((N_ + 3) / 4, B_ * P_, 2), 256, 0, stream>>>(
        qkva, qkvb, Tm, Am, atta, attb);
    k_spatial_fuse_qkv<<<T_ / 4, 64, 0, stream>>>(atta, attb, x1f,
        gs0_W1, gs0_W2, gs1_W1, gs1_W2, g2_W1, g2_W2,
        sws_wg, sws_bg, sws_wo, sws_bo, lns_g, lns_b,
        enc, wq, wk, wv, x2f, qkva);

    // ---- stage 3: temporal enc-dec attention + fused tail + FFN ----
    k_temporal<<<B_ * N_, 768, 0, stream>>>(qkva, atta);
    k_gsl_ffn<<<T_ / 4, 64, 0, stream>>>(atta, x2f, ge_W1, ge_W2, swe_wg, swe_bg,
                                         swe_wo, swe_bo, lne_g, lne_b,
                                         f_w1, f_b1, f_w2, f_b2, lnf_g, lnf_b,
                                         (float*)d_out);
}

// Round 11
// 292.271 us; speedup vs baseline: 1.2747x; 1.2747x over previous
//
#include <hip/hip_runtime.h>
#include <hip/hip_bf16.h>
#include <math.h>

namespace {

constexpr int B_ = 2, P_ = 12, N_ = 170, DM_ = 64, H_ = 8, DK_ = 8, DH_ = 32, DF_ = 256;
constexpr int T_ = B_ * P_ * N_;        // 4080 tokens
constexpr float SQRT_DK = 2.8284271247461903f;

constexpr int NG_ = 12;                 // 192 output cols / 16
constexpr int NC_ = 66;                 // 2112 K / 32
constexpr int WFRAG_G = NG_ * NC_ * 64 * 8;   // shorts per graph = 405504

typedef __attribute__((ext_vector_type(4))) short short4v;
typedef __attribute__((ext_vector_type(8))) short short8v;
typedef __attribute__((ext_vector_type(4))) float float4v;

// float -> bf16 bits, round-to-nearest-even
__device__ __forceinline__ unsigned short f2bf(float x) {
    union { float f; unsigned int u; } c; c.f = x;
    unsigned int r = (c.u + 0x7FFFu + ((c.u >> 16) & 1u)) >> 16;
    return (unsigned short)r;
}

// ---------- merged one-time prep: w2/b2 permute (y==0) + 3x meta hidden (y>=1) ----------
__global__ void k_pre(const float* __restrict__ c_x,
                      const float* __restrict__ w1a, const float* __restrict__ b1a,
                      const float* __restrict__ w1b, const float* __restrict__ b1b,
                      const float* __restrict__ w1c, const float* __restrict__ b1c,
                      const float* __restrict__ w2a, const float* __restrict__ b2a,
                      const float* __restrict__ w2b, const float* __restrict__ b2b,
                      const float* __restrict__ w2c, const float* __restrict__ b2c,
                      float* __restrict__ hra, float* __restrict__ hrb,
                      float* __restrict__ hrc, unsigned short* __restrict__ Wfrag) {
    if (blockIdx.y == 0) {
        int idx = blockIdx.x * 256 + threadIdx.x;   // ((g*12+ng)*66+c)*64 + lane
        if (idx >= 3 * NG_ * NC_ * 64) return;
        int lane = idx & 63;
        int c = (idx >> 6) % NC_;
        int ng = (idx >> 6) / NC_ % NG_;
        int g = idx / (64 * NC_ * NG_);
        const float* w2 = g == 0 ? w2a : (g == 1 ? w2b : w2c);
        const float* b2 = g == 0 ? b2a : (g == 1 ? b2b : b2c);
        int m = ng * 16 + (lane & 15);
        int u = c >> 1;                              // jh
        int d0 = (c & 1) * 32 + (lane >> 4) * 8;
        const float* src = (u < DH_) ? (w2 + u * 12288 + m * 64 + d0) : (b2 + m * 64 + d0);
        short8v o;
        #pragma unroll
        for (int j = 0; j < 8; ++j) o[j] = (short)f2bf(src[j]);
        *(short8v*)(Wfrag + (size_t)idx * 8) = o;
    } else {
        int z = blockIdx.y - 1;
        const float* w1 = z == 0 ? w1a : (z == 1 ? w1b : w1c);
        const float* b1 = z == 0 ? b1a : (z == 1 ? b1b : b1c);
        float* hr = z == 0 ? hra : (z == 1 ? hrb : hrc);
        int idx = blockIdx.x * 256 + threadIdx.x;          // t*32 + j
        if (idx >= T_ * DH_) return;
        int t = idx / DH_, j = idx % DH_;
        float acc = b1[j];
        const float* cx = c_x + t * DM_;
        #pragma unroll
        for (int d = 0; d < DM_; ++d) acc += cx[d] * w1[d * DH_ + j];
        hr[idx] = fmaxf(acc, 0.f);
    }
}

// ---------- meta+mhlin GEMM v5: 32-col tiles (2x waves), 2-deep register prefetch ----------
__global__ __launch_bounds__(256) void k_meta_gemm2(
    const float* __restrict__ hr0, const float* __restrict__ hr1,
    const float* __restrict__ xin,
    const unsigned short* __restrict__ Wf0, const unsigned short* __restrict__ Wf1,
    float* __restrict__ out0, float* __restrict__ out1) {
    const int bz = blockIdx.z;
    const float* hr = bz ? hr1 : hr0;
    const unsigned short* Wf = bz ? Wf1 : Wf0;
    float* out = bz ? out1 : out0;

    const int tid = threadIdx.x;
    const int wv = tid >> 6, lane = tid & 63;
    const int l15 = lane & 15, quad = lane >> 4;
    const int g16 = blockIdx.x * 4 + wv;
    if (g16 >= 255) return;                      // 255 groups of 16 tokens; no barriers
    const int t = g16 * 16 + l15;
    const int nb = blockIdx.y;                   // 0..5 (32 cols each)

    const float* xp = xin + t * 64 + quad * 8;
    float4v xa = *(const float4v*)(xp);
    float4v xb = *(const float4v*)(xp + 4);
    float4v xc = *(const float4v*)(xp + 32);
    float4v xd = *(const float4v*)(xp + 36);
    float xr[16] = {xa.x, xa.y, xa.z, xa.w, xb.x, xb.y, xb.z, xb.w,
                    xc.x, xc.y, xc.z, xc.w, xd.x, xd.y, xd.z, xd.w};

    const float* hrp = hr + t * 32;
    float hrbuf[32];
    #pragma unroll
    for (int i = 0; i < 8; ++i) {
        float4v h4 = *(const float4v*)(hrp + i * 4);
        hrbuf[i * 4 + 0] = h4.x; hrbuf[i * 4 + 1] = h4.y;
        hrbuf[i * 4 + 2] = h4.z; hrbuf[i * 4 + 3] = h4.w;
    }

    float4v acc[2] = {{0.f,0.f,0.f,0.f},{0.f,0.f,0.f,0.f}};

    const unsigned short* wb = Wf + ((size_t)(nb * 2) * NC_ * 64 + lane) * 8;
    const size_t qstride = (size_t)NC_ * 64 * 8;   // ng -> ng+1
    const size_t cstride = 64 * 8;                 // c -> c+1

    short8v b[2][4];
    {
        const unsigned short* wc = wb;
        #pragma unroll
        for (int q = 0; q < 2; ++q) {
            b[0][2 * q]     = *(const short8v*)(wc + q * qstride);
            b[0][2 * q + 1] = *(const short8v*)(wc + q * qstride + cstride);
        }
    }
    #pragma unroll
    for (int u = 0; u < 33; ++u) {
        const int cur = u & 1, nxt = cur ^ 1;
        if (u + 1 < 33) {       // issue next-step loads FIRST (hidden under compute)
            const unsigned short* wc = wb + (size_t)(2 * (u + 1)) * cstride;
            #pragma unroll
            for (int q = 0; q < 2; ++q) {
                b[nxt][2 * q]     = *(const short8v*)(wc + q * qstride);
                b[nxt][2 * q + 1] = *(const short8v*)(wc + q * qstride + cstride);
            }
        }
        float hrv = (u < 32) ? hrbuf[u] : 1.0f;    // u=32: bias row
        short8v a0, a1;
        #pragma unroll
        for (int j = 0; j < 8; ++j) {
            a0[j] = (short)f2bf(hrv * xr[j]);
            a1[j] = (short)f2bf(hrv * xr[8 + j]);
        }
        #pragma unroll
        for (int q = 0; q < 2; ++q) {
            acc[q] = __builtin_amdgcn_mfma_f32_16x16x32_bf16(a0, b[cur][2 * q],     acc[q], 0, 0, 0);
            acc[q] = __builtin_amdgcn_mfma_f32_16x16x32_bf16(a1, b[cur][2 * q + 1], acc[q], 0, 0, 0);
        }
    }

    // D: col=lane&15 (n), row=quad*4+r (token)  [learn_hip m89/m91]
    #pragma unroll
    for (int q = 0; q < 2; ++q) {
        #pragma unroll
        for (int r = 0; r < 4; ++r) {
            int tt = g16 * 16 + quad * 4 + r;
            out[tt * 192 + nb * 32 + q * 16 + l15] = acc[q][r];
        }
    }
}

// ---------- retnet retention v3: 768 thr, wave = one q, S staged once ----------
__global__ __launch_bounds__(768) void k_retnet(const float* __restrict__ qkv,
                                                const float* __restrict__ Dm,
                                                float* __restrict__ att) {
    const int bn = blockIdx.x;           // b*N + n
    const int b = bn / N_, n = bn % N_;
    __shared__ float S[12][192];
    __shared__ float Ds[8 * 145];
    const int tid = threadIdx.x;
    for (int e = tid; e < 12 * 192; e += 768) {
        int p = e / 192, c = e % 192;
        S[p][c] = qkv[((size_t)((b * P_ + p) * N_ + n)) * 192 + c];
    }
    for (int e = tid; e < 1152; e += 768) {
        Ds[(e / 144) * 145 + (e % 144)] = Dm[e];
    }
    __syncthreads();
    const int q = tid >> 6;              // wave index == q (0..11)
    const int lane = tid & 63;
    const int h = lane >> 3, k = lane & 7;
    float Qv = S[q][h * 8 + k];
    float r[P_];
    float rsum = 0.f;
    #pragma unroll
    for (int p = 0; p < P_; ++p) {
        float prod = Qv * S[p][64 + h * 8 + k];
        prod += __shfl_xor(prod, 1, 64);
        prod += __shfl_xor(prod, 2, 64);
        prod += __shfl_xor(prod, 4, 64);
        float s = (prod / SQRT_DK) * Ds[h * 145 + q * 12 + p];
        r[p] = s; rsum += s;
    }
    float rs = fmaxf(fabsf(rsum), 1.0f);
    float acc = 0.f;
    #pragma unroll
    for (int p = 0; p < P_; ++p) acc += (r[p] / rs) * S[p][128 + h * 8 + k];
    att[((size_t)((b * P_ + q) * N_ + n)) * 64 + lane] = acc;
}

// ---------- temporal enc-dec attention v3: 768 thr, wave = one q ----------
__global__ __launch_bounds__(768) void k_temporal(const float* __restrict__ qkv,
                                                  float* __restrict__ att) {
    const int bn = blockIdx.x;
    const int b = bn / N_, n = bn % N_;
    __shared__ float S[12][192];
    const int tid = threadIdx.x;
    for (int e = tid; e < 12 * 192; e += 768) {
        int p = e / 192, c = e % 192;
        S[p][c] = qkv[((size_t)((b * P_ + p) * N_ + n)) * 192 + c];
    }
    __syncthreads();
    const int q = tid >> 6;
    const int lane = tid & 63;
    const int h = lane >> 3, k = lane & 7;
    float Qv = S[q][h * 8 + k];
    float s[P_];
    float mx = -1e30f;
    #pragma unroll
    for (int p = 0; p < P_; ++p) {
        float prod = Qv * S[p][64 + h * 8 + k];
        prod += __shfl_xor(prod, 1, 64);
        prod += __shfl_xor(prod, 2, 64);
        prod += __shfl_xor(prod, 4, 64);
        float v = prod / SQRT_DK;
        s[p] = v; mx = fmaxf(mx, v);
    }
    float den = 0.f, acc = 0.f;
    #pragma unroll
    for (int p = 0; p < P_; ++p) {
        float e = expf(s[p] - mx);
        den += e;
        acc += e * S[p][128 + h * 8 + k];
    }
    att[((size_t)((b * P_ + q) * N_ + n)) * 64 + lane] = acc / den;
}

// ---------- spatial attention: SPARSE. one wave per (g, bp, row i) ----------
__global__ __launch_bounds__(256) void k_spatial_sparse(
    const float* __restrict__ qkvA, const float* __restrict__ qkvB,
    const float* __restrict__ Tm, const float* __restrict__ Am,
    float* __restrict__ attA, float* __restrict__ attB) {
    const int bp = blockIdx.y;          // 0..23
    const int g = blockIdx.z;           // 0: predefined T, 1: adaptive A
    const float* qkv = g ? qkvB : qkvA;
    float* att = g ? attB : attA;

    __shared__ int2 elist[4][176];      // per-wave (j, weight-bits)

    const int tid = threadIdx.x;
    const int wv = tid >> 6, lane = tid & 63;
    const int i = blockIdx.x * 4 + wv;
    if (i >= N_) return;                // no __syncthreads anywhere: safe

    int2* el = elist[wv];
    const float* Trow = g ? (Am + (size_t)(bp * N_ + i) * N_) : (Tm + (size_t)i * N_);
    int nnz = 0;
    #pragma unroll
    for (int c = 0; c < 3; ++c) {
        int j = c * 64 + lane;
        float w = (j < N_) ? Trow[j] : 0.f;
        unsigned long long m = __ballot(w != 0.f);
        if (w != 0.f) {
            int pos = nnz + (int)__popcll(m & ((1ull << lane) - 1ull));
            el[pos] = make_int2(j, __float_as_int(w));
        }
        nnz += (int)__popcll(m);
    }

    const float q = qkv[(size_t)(bp * N_ + i) * 192 + lane];  // Q[i, h*8+k]
    float m = 0.f;                       // masked zeros enter the row max
    float den = 0.f, acc = 0.f;
    int e = 0;
    for (; e + 1 < nnz; e += 2) {
        int2 e0 = el[e], e1 = el[e + 1];
        const float* r0 = qkv + (size_t)(bp * N_ + e0.x) * 192;
        const float* r1 = qkv + (size_t)(bp * N_ + e1.x) * 192;
        float k0 = r0[64 + lane], v0 = r0[128 + lane];
        float k1 = r1[64 + lane], v1 = r1[128 + lane];
        float p0 = q * k0, p1 = q * k1;
        p0 += __shfl_xor(p0, 1, 64); p1 += __shfl_xor(p1, 1, 64);
        p0 += __shfl_xor(p0, 2, 64); p1 += __shfl_xor(p1, 2, 64);
        p0 += __shfl_xor(p0, 4, 64); p1 += __shfl_xor(p1, 4, 64);
        float s0 = p0 / SQRT_DK, s1 = p1 / SQRT_DK;
        float mn = fmaxf(m, fmaxf(s0, s1));          // -> v_max3
        float cs = expf(m - mn);
        float x0 = (s0 != 0.f) ? expf(s0 - mn) : 0.f;
        float x1 = (s1 != 0.f) ? expf(s1 - mn) : 0.f;
        den = den * cs + x0 + x1;
        acc = acc * cs + x0 * __int_as_float(e0.y) * v0
                       + x1 * __int_as_float(e1.y) * v1;
        m = mn;
    }
    if (e < nnz) {
        int2 e0 = el[e];
        const float* r0 = qkv + (size_t)(bp * N_ + e0.x) * 192;
        float k0 = r0[64 + lane], v0 = r0[128 + lane];
        float p0 = q * k0;
        p0 += __shfl_xor(p0, 1, 64);
        p0 += __shfl_xor(p0, 2, 64);
        p0 += __shfl_xor(p0, 4, 64);
        float s0 = p0 / SQRT_DK;
        float mn = fmaxf(m, s0);
        float cs = expf(m - mn);
        float x0 = (s0 != 0.f) ? expf(s0 - mn) : 0.f;
        den = den * cs + x0;
        acc = acc * cs + x0 * __int_as_float(e0.y) * v0;
    }

    att[(size_t)(bp * N_ + i) * 64 + lane] = acc / (den + 1e-5f);
}

// ---------- gdc8 for TWO tokens sharing each weight load ----------
__device__ __forceinline__ void gdc8x2(const float* dv0, const float* dv1,
                                       const float* W1, const float* W2, int dm,
                                       float& out0, float& out1) {
    float a0[8], s0[8], a1[8], s1[8];
    #pragma unroll
    for (int g = 0; g < 8; ++g) {
        float aa0 = 0.f, ss0 = 0.f, aa1 = 0.f, ss1 = 0.f;
        #pragma unroll
        for (int c = 0; c < 8; ++c) {
            float w1v = W1[(g * 8 + c) * 64 + dm];
            float w2v = W2[(g * 8 + c) * 64 + dm];
            float d0 = dv0[g * 8 + c], d1 = dv1[g * 8 + c];
            aa0 += d0 * w1v; ss0 += d0 * w2v;
            aa1 += d1 * w1v; ss1 += d1 * w2v;
        }
        a0[g] = aa0; s0[g] = fmaxf(ss0, 0.f);
        a1[g] = aa1; s1[g] = fmaxf(ss1, 0.f);
    }
    float mx0 = s0[0], mx1 = s1[0];
    #pragma unroll
    for (int g = 1; g < 8; ++g) { mx0 = fmaxf(mx0, s0[g]); mx1 = fmaxf(mx1, s1[g]); }
    float den0 = 0.f, o0 = 0.f, den1 = 0.f, o1 = 0.f;
    #pragma unroll
    for (int g = 0; g < 8; ++g) {
        float e0 = expf(s0[g] - mx0); den0 += e0; o0 += a0[g] * e0;
        float e1 = expf(s1[g] - mx1); den1 += e1; o1 += a1[g] * e1;
    }
    out0 = o0 / den0; out1 = o1 / den1;
}

__device__ __forceinline__ float ln_out(float r, int dm, const float* g, const float* b) {
    float m = r, m2 = r * r;
    #pragma unroll
    for (int off = 32; off; off >>= 1) { m += __shfl_xor(m, off, 64); m2 += __shfl_xor(m2, off, 64); }
    m *= (1.f / 64.f); m2 *= (1.f / 64.f);
    float var = m2 - m * m;
    return (r - m) * rsqrtf(var + 1e-5f) * g[dm] + b[dm];
}

// ---------- gdc + swish + residual + LN, 2 tokens/wave (weight loads shared) ----------
__global__ __launch_bounds__(64) void k_gsl(const float* __restrict__ att,
    const float* __restrict__ xin,
    const float* W1, const float* W2,
    const float* wg, const float* bg,
    const float* wo, const float* bo,
    const float* lng, const float* lnb, float* __restrict__ xout) {
    const int t0 = blockIdx.x * 2, dm = threadIdx.x;
    __shared__ float dv0[64], dv1[64], xv0[64], xv1[64], sw0[64], sw1[64];
    dv0[dm] = att[t0 * 64 + dm];       dv1[dm] = att[t0 * 64 + 64 + dm];
    xv0[dm] = xin[t0 * 64 + dm];       xv1[dm] = xin[t0 * 64 + 64 + dm];
    __syncthreads();
    float o0, o1;
    gdc8x2(dv0, dv1, W1, W2, dm, o0, o1);
    float hg0 = bg[dm], hg1 = hg0;
    #pragma unroll
    for (int d = 0; d < 64; ++d) {
        float w = wg[d * 64 + dm];
        hg0 += xv0[d] * w; hg1 += xv1[d] * w;
    }
    hg0 *= o0; hg1 *= o1;
    sw0[dm] = hg0 / (1.f + expf(-hg0));
    sw1[dm] = hg1 / (1.f + expf(-hg1));
    __syncthreads();
    float ov0 = bo[dm], ov1 = ov0;
    #pragma unroll
    for (int d = 0; d < 64; ++d) {
        float w = wo[d * 64 + dm];
        ov0 += sw0[d] * w; ov1 += sw1[d] * w;
    }
    xout[t0 * 64 + dm]      = ln_out(ov0 + xv0[dm], dm, lng, lnb);
    xout[t0 * 64 + 64 + dm] = ln_out(ov1 + xv1[dm], dm, lng, lnb);
}

// ---------- spatial tail + qkv proj, 2 tokens/wave ----------
__global__ __launch_bounds__(64) void k_spatial_fuse_qkv(
    const float* __restrict__ att0, const float* __restrict__ att1,
    const float* __restrict__ x1,
    const float* gs0_W1, const float* gs0_W2,
    const float* gs1_W1, const float* gs1_W2,
    const float* g2_W1, const float* g2_W2,
    const float* wg, const float* bg,
    const float* wo, const float* bo,
    const float* lng, const float* lnb,
    const float* __restrict__ enc,
    const float* wqm, const float* wkm, const float* wvm,
    float* __restrict__ x2f, float* __restrict__ qkv) {
    const int t0 = blockIdx.x * 2, dm = threadIdx.x;
    __shared__ float d00[64], d01[64], d10[64], d11[64];     // d{graph}{tok}
    __shared__ float xv0[64], xv1[64], ev0[64], ev1[64];
    __shared__ float o00[64], o01[64], o10[64], o11[64];     // o{graph}{tok}
    __shared__ float sw0[64], sw1[64], x20[64], x21[64];
    d00[dm] = att0[t0 * 64 + dm];  d01[dm] = att0[t0 * 64 + 64 + dm];
    d10[dm] = att1[t0 * 64 + dm];  d11[dm] = att1[t0 * 64 + 64 + dm];
    xv0[dm] = x1[t0 * 64 + dm];    xv1[dm] = x1[t0 * 64 + 64 + dm];
    ev0[dm] = enc[t0 * 64 + dm];   ev1[dm] = enc[t0 * 64 + 64 + dm];
    __syncthreads();
    float g00, g01, g10, g11;
    gdc8x2(d00, d01, gs0_W1, gs0_W2, dm, g00, g01);
    gdc8x2(d10, d11, gs1_W1, gs1_W2, dm, g10, g11);
    o00[dm] = g00; o01[dm] = g01; o10[dm] = g10; o11[dm] = g11;
    __syncthreads();
    // g2 (G=2, C=64) for both tokens, 4 weight loads per c shared
    float a0t0 = 0.f, s0t0 = 0.f, a1t0 = 0.f, s1t0 = 0.f;
    float a0t1 = 0.f, s0t1 = 0.f, a1t1 = 0.f, s1t1 = 0.f;
    #pragma unroll
    for (int c = 0; c < 64; ++c) {
        float wA0 = g2_W1[c * 64 + dm],        wS0 = g2_W2[c * 64 + dm];
        float wA1 = g2_W1[(64 + c) * 64 + dm], wS1 = g2_W2[(64 + c) * 64 + dm];
        float v00 = o00[c], v01 = o01[c], v10 = o10[c], v11 = o11[c];
        a0t0 += v00 * wA0; s0t0 += v00 * wS0; a1t0 += v10 * wA1; s1t0 += v10 * wS1;
        a0t1 += v01 * wA0; s0t1 += v01 * wS0; a1t1 += v11 * wA1; s1t1 += v11 * wS1;
    }
    float o_t0, o_t1;
    {
        float p = fmaxf(s0t0, 0.f), qv = fmaxf(s1t0, 0.f);
        float mx = fmaxf(p, qv);
        float e0 = expf(p - mx), e1 = expf(qv - mx);
        o_t0 = (a0t0 * e0 + a1t0 * e1) / (e0 + e1);
    }
    {
        float p = fmaxf(s0t1, 0.f), qv = fmaxf(s1t1, 0.f);
        float mx = fmaxf(p, qv);
        float e0 = expf(p - mx), e1 = expf(qv - mx);
        o_t1 = (a0t1 * e0 + a1t1 * e1) / (e0 + e1);
    }
    float hg0 = bg[dm], hg1 = hg0;
    #pragma unroll
    for (int d = 0; d < 64; ++d) {
        float w = wg[d * 64 + dm];
        hg0 += xv0[d] * w; hg1 += xv1[d] * w;
    }
    hg0 *= o_t0; hg1 *= o_t1;
    sw0[dm] = hg0 / (1.f + expf(-hg0));
    sw1[dm] = hg1 / (1.f + expf(-hg1));
    __syncthreads();
    float ov0 = bo[dm], ov1 = ov0;
    #pragma unroll
    for (int d = 0; d < 64; ++d) {
        float w = wo[d * 64 + dm];
        ov0 += sw0[d] * w; ov1 += sw1[d] * w;
    }
    float r0 = ln_out(ov0 + xv0[dm], dm, lng, lnb);
    float r1 = ln_out(ov1 + xv1[dm], dm, lng, lnb);
    x2f[t0 * 64 + dm] = r0;       x2f[t0 * 64 + 64 + dm] = r1;
    x20[dm] = r0;                 x21[dm] = r1;
    __syncthreads();
    // q/k/v projections (q from x2, k/v from enc), weight loads shared
    float aq0 = 0.f, ak0 = 0.f, av0 = 0.f, aq1 = 0.f, ak1 = 0.f, av1 = 0.f;
    #pragma unroll
    for (int d = 0; d < 64; ++d) {
        float wq_ = wqm[d * 64 + dm];
        float wk_ = wkm[d * 64 + dm];
        float wv_ = wvm[d * 64 + dm];
        aq0 += x20[d] * wq_; aq1 += x21[d] * wq_;
        ak0 += ev0[d] * wk_; ak1 += ev1[d] * wk_;
        av0 += ev0[d] * wv_; av1 += ev1[d] * wv_;
    }
    qkv[t0 * 192 + dm] = aq0;
    qkv[t0 * 192 + 64 + dm] = ak0;
    qkv[t0 * 192 + 128 + dm] = av0;
    qkv[(t0 + 1) * 192 + dm] = aq1;
    qkv[(t0 + 1) * 192 + 64 + dm] = ak1;
    qkv[(t0 + 1) * 192 + 128 + dm] = av1;
}

// ---------- stage-3 tail + FFN, 2 tokens/wave (x3 never hits global) ----------
__global__ __launch_bounds__(64) void k_gsl_ffn(const float* __restrict__ att,
    const float* __restrict__ xin,
    const float* W1, const float* W2,
    const float* wg, const float* bg,
    const float* wo, const float* bo,
    const float* lng, const float* lnb,
    const float* w1, const float* b1,
    const float* w2, const float* b2,
    const float* lnfg, const float* lnfb,
    float* __restrict__ out) {
    const int t0 = blockIdx.x * 2, dm = threadIdx.x;
    __shared__ float dv0[64], dv1[64], xv0[64], xv1[64], sw0[64], sw1[64];
    __shared__ float x30[64], x31[64], hv0[256], hv1[256];
    dv0[dm] = att[t0 * 64 + dm];   dv1[dm] = att[t0 * 64 + 64 + dm];
    xv0[dm] = xin[t0 * 64 + dm];   xv1[dm] = xin[t0 * 64 + 64 + dm];
    __syncthreads();
    float o0, o1;
    gdc8x2(dv0, dv1, W1, W2, dm, o0, o1);
    float hg0 = bg[dm], hg1 = hg0;
    #pragma unroll
    for (int d = 0; d < 64; ++d) {
        float w = wg[d * 64 + dm];
        hg0 += xv0[d] * w; hg1 += xv1[d] * w;
    }
    hg0 *= o0; hg1 *= o1;
    sw0[dm] = hg0 / (1.f + expf(-hg0));
    sw1[dm] = hg1 / (1.f + expf(-hg1));
    __syncthreads();
    float ov0 = bo[dm], ov1 = ov0;
    #pragma unroll
    for (int d = 0; d < 64; ++d) {
        float w = wo[d * 64 + dm];
        ov0 += sw0[d] * w; ov1 += sw1[d] * w;
    }
    float x3_0 = ln_out(ov0 + xv0[dm], dm, lng, lnb);
    float x3_1 = ln_out(ov1 + xv1[dm], dm, lng, lnb);
    x30[dm] = x3_0; x31[dm] = x3_1;
    __syncthreads();
    // ---- FFN, w1 loads shared across both tokens ----
    #pragma unroll
    for (int e = 0; e < 4; ++e) {
        int j = e * 64 + dm;
        float a0 = b1[j], a1 = a0;
        #pragma unroll
        for (int d = 0; d < 64; ++d) {
            float w = w1[d * 256 + j];
            a0 += x30[d] * w; a1 += x31[d] * w;
        }
        hv0[j] = fmaxf(a0, 0.f);
        hv1[j] = fmaxf(a1, 0.f);
    }
    __syncthreads();
    float a0 = b2[dm], a1 = a0;
    for (int j = 0; j < 256; ++j) {
        float w = w2[j * 64 + dm];
        a0 += hv0[j] * w; a1 += hv1[j] * w;
    }
    out[t0 * 64 + dm]      = ln_out(a0 + x3_0, dm, lnfg, lnfb);
    out[t0 * 64 + 64 + dm] = ln_out(a1 + x3_1, dm, lnfg, lnfb);
}

} // namespace

extern "C" void kernel_launch(void* const* d_in, const int* in_sizes, int n_in,
                              void* d_out, int out_size, void* d_ws, size_t ws_size,
                              hipStream_t stream) {
    (void)in_sizes; (void)n_in; (void)out_size; (void)ws_size;
    const float* x    = (const float*)d_in[0];
    const float* c_x  = (const float*)d_in[1];
    const float* enc  = (const float*)d_in[2];
    const float* Tm   = (const float*)d_in[3];
    const float* Am   = (const float*)d_in[4];
    const float* Dm   = (const float*)d_in[5];
    const float* mr_w1 = (const float*)d_in[6];
    const float* mr_b1 = (const float*)d_in[7];
    const float* mr_w2 = (const float*)d_in[8];
    const float* mr_b2 = (const float*)d_in[9];
    const float* ms0_w1 = (const float*)d_in[10];
    const float* ms0_b1 = (const float*)d_in[11];
    const float* ms0_w2 = (const float*)d_in[12];
    const float* ms0_b2 = (const float*)d_in[13];
    const float* ms1_w1 = (const float*)d_in[14];
    const float* ms1_b1 = (const float*)d_in[15];
    const float* ms1_w2 = (const float*)d_in[16];
    const float* ms1_b2 = (const float*)d_in[17];
    const float* gr_W1 = (const float*)d_in[18];
    const float* gr_W2 = (const float*)d_in[19];
    const float* gs0_W1 = (const float*)d_in[20];
    const float* gs0_W2 = (const float*)d_in[21];
    const float* gs1_W1 = (const float*)d_in[22];
    const float* gs1_W2 = (const float*)d_in[23];
    const float* g2_W1 = (const float*)d_in[24];
    const float* g2_W2 = (const float*)d_in[25];
    const float* ge_W1 = (const float*)d_in[26];
    const float* ge_W2 = (const float*)d_in[27];
    const float* swr_wg = (const float*)d_in[28];
    const float* swr_bg = (const float*)d_in[29];
    const float* swr_wo = (const float*)d_in[30];
    const float* swr_bo = (const float*)d_in[31];
    const float* sws_wg = (const float*)d_in[32];
    const float* sws_bg = (const float*)d_in[33];
    const float* sws_wo = (const float*)d_in[34];
    const float* sws_bo = (const float*)d_in[35];
    const float* swe_wg = (const float*)d_in[36];
    const float* swe_bg = (const float*)d_in[37];
    const float* swe_wo = (const float*)d_in[38];
    const float* swe_bo = (const float*)d_in[39];
    const float* lnr_g = (const float*)d_in[40];
    const float* lnr_b = (const float*)d_in[41];
    const float* lns_g = (const float*)d_in[42];
    const float* lns_b = (const float*)d_in[43];
    const float* lne_g = (const float*)d_in[44];
    const float* lne_b = (const float*)d_in[45];
    const float* lnf_g = (const float*)d_in[46];
    const float* lnf_b = (const float*)d_in[47];
    const float* wq = (const float*)d_in[48];
    const float* wk = (const float*)d_in[49];
    const float* wv = (const float*)d_in[50];
    const float* f_w1 = (const float*)d_in[51];
    const float* f_b1 = (const float*)d_in[52];
    const float* f_w2 = (const float*)d_in[53];
    const float* f_b2 = (const float*)d_in[54];

    // workspace layout (~16.2 MB)
    float* ws   = (float*)d_ws;
    float* hr   = ws;                 // stage-2 graph0 hr
    float* hr2  = hr   + T_ * DH_;    // stage-2 graph1 hr
    float* qkva = hr2  + T_ * DH_;
    float* qkvb = qkva + T_ * 192;
    float* atta = qkvb + T_ * 192;
    float* attb = atta + T_ * DM_;    // also reused as stage-1 hr buffer
    float* x1f  = attb + T_ * DM_;
    float* x2f  = x1f  + T_ * DM_;
    float* x3f  = x2f  + T_ * DM_;    // unused now (kept for layout stability)
    unsigned short* Wfrag = (unsigned short*)(x3f + T_ * DM_);  // 3 graphs, 2.4 MB
    float* hr_r = attb;               // consumed before k_spatial_sparse writes attb

    // one launch: w2/b2 permute (y=0) + all three meta-hiddens (y=1..3)
    k_pre<<<dim3(594, 4), 256, 0, stream>>>(
        c_x, mr_w1, mr_b1, ms0_w1, ms0_b1, ms1_w1, ms1_b1,
        mr_w2, mr_b2, ms0_w2, ms0_b2, ms1_w2, ms1_b2,
        hr_r, hr, hr2, Wfrag);

    // ---- stage 1: retnet retention ----
    k_meta_gemm2<<<dim3(64, 6, 1), 256, 0, stream>>>(
        hr_r, hr_r, x, Wfrag, Wfrag, qkva, qkva);
    k_retnet<<<B_ * N_, 768, 0, stream>>>(qkva, Dm, atta);
    k_gsl<<<T_ / 2, 64, 0, stream>>>(atta, x, gr_W1, gr_W2, swr_wg, swr_bg,
                                     swr_wo, swr_bo, lnr_g, lnr_b, x1f);

    // ---- stage 2: spatial (sparse edge walk) + fused tail + qkv projection ----
    k_meta_gemm2<<<dim3(64, 6, 2), 256, 0, stream>>>(
        hr, hr2, x1f, Wfrag + WFRAG_G, Wfrag + 2 * WFRAG_G, qkva, qkvb);
    k_spatial_sparse<<<dim3((N_ + 3) / 4, B_ * P_, 2), 256, 0, stream>>>(
        qkva, qkvb, Tm, Am, atta, attb);
    k_spatial_fuse_qkv<<<T_ / 2, 64, 0, stream>>>(atta, attb, x1f,
        gs0_W1, gs0_W2, gs1_W1, gs1_W2, g2_W1, g2_W2,
        sws_wg, sws_bg, sws_wo, sws_bo, lns_g, lns_b,
        enc, wq, wk, wv, x2f, qkva);

    // ---- stage 3: temporal enc-dec attention + fused tail + FFN ----
    k_temporal<<<B_ * N_, 768, 0, stream>>>(qkva, atta);
    k_gsl_ffn<<<T_ / 2, 64, 0, stream>>>(atta, x2f, ge_W1, ge_W2, swe_wg, swe_bg,
                                         swe_wo, swe_bo, lne_g, lne_b,
                                         f_w1, f_b1, f_w2, f_b2, lnf_g, lnf_b,
                                         (float*)d_out);
}